// Round 12
// baseline (39.865 us; speedup 1.0000x reference)
//
#include <hip/hip_runtime.h>

typedef __fp16       pk16x2 __attribute__((ext_vector_type(2)));
typedef _Float16     f16x8  __attribute__((ext_vector_type(8)));
typedef float        f32x4  __attribute__((ext_vector_type(4)));
typedef float        f32x16 __attribute__((ext_vector_type(16)));
typedef unsigned int u32x4  __attribute__((ext_vector_type(4)));

#define BATCH 65536
#define NIN   128
#define NOUT  128

#define L2E   1.4426950408889634f
#define SQL2E 1.2011224087864498f     /* sqrt(log2 e) */
#define EM2   0.1353352832366127f     /* e^-2 */

// ---------------------------------------------------------------------------
// MFMA 32x32x16 f16. A-frag: lane -> row = l&31, k = (l>>5)*8 + e.
// B-frag: lane -> col = l&31, k = (l>>5)*8 + e. C/D: col = l&31,
// row = (reg&3) + 8*(reg>>2) + 4*(l>>5).
//
// K-order (72 ksteps of 16): basis ks = g*8 + t2 (g=0..7):
//   k-slot sub*8+e -> j = g*16 + sub*8 + t2, grid = e
//   (lane consumes 8 CONSECUTIVE x floats per group). silu ks = 64+s:
//   j = s*16 + sub*8 + e.
//
// W3 (kan_prep): 72 tiles x 4 KB; tile ks, chunk c = nbb*64 + lane (16 B):
//   col = nbb*32 + (lane&31), sub = lane>>5:
//     ks < 64 : coeffs[col][(ks>>3)*16 + sub*8 + (ks&7)][e]
//     ks >= 64: base_w[col][(ks-64)*16 + sub*8 + e]
// Fragment ds_read: 64 lanes x 16 B consecutive -> conflict-free (verified).
//
// R12: (1) s_sleep time-stagger so co-resident blocks run anti-phased;
// (2) A-gen software-pipelined INTO the MFMA stream (no VALU burst);
// (3) f16x8 built by dword bit_casts of cvt_pkrtz (no element inserts).
// ---------------------------------------------------------------------------

__global__ __launch_bounds__(256) void kan_prep(const float* __restrict__ coeffs,
                                                const float* __restrict__ base_w,
                                                _Float16* __restrict__ W3) {
    int t = blockIdx.x * 256 + threadIdx.x;   // chunk id, 0..18431
    int ks   = t >> 8;
    int c    = t & 255;
    int nbb  = c >> 6;
    int lane = c & 63;
    int sub  = lane >> 5;
    int col  = nbb * 32 + (lane & 31);
    f16x8 v;
    if (ks < 64) {
        int g = ks >> 3, t2 = ks & 7;
        const float* src = coeffs + ((size_t)col * 128 + g * 16 + sub * 8 + t2) * 8;
#pragma unroll
        for (int e = 0; e < 8; ++e) v[e] = (_Float16)src[e];
    } else {
        const float* src = base_w + (size_t)col * 128 + (ks - 64) * 16 + sub * 8;
#pragma unroll
        for (int e = 0; e < 8; ++e) v[e] = (_Float16)src[e];
    }
    *(f16x8*)((char*)W3 + (size_t)t * 16) = v;
}

__device__ __forceinline__ void gll16(const void* g, void* l) {
    __builtin_amdgcn_global_load_lds(
        (const __attribute__((address_space(1))) unsigned int*)g,
        (__attribute__((address_space(3))) unsigned int*)l, 16, 0, 0);
}

// b_g = exp(-(t-g)^2), t = 3.5*(x+1): 2 exp + mul chain; dword-packed result.
__device__ __forceinline__ f16x8 basis8r(float t) {
    float u  = t * SQL2E;
    float b0 = __builtin_amdgcn_exp2f(-(u * u));                              // e^{-t^2}
    float r  = __builtin_amdgcn_exp2f(__builtin_fmaf(t, 2.0f * L2E, -L2E));   // e^{2t-1}
    float b1 = b0 * r; r *= EM2;
    float b2 = b1 * r; r *= EM2;
    float b3 = b2 * r; r *= EM2;
    float b4 = b3 * r; r *= EM2;
    float b5 = b4 * r; r *= EM2;
    float b6 = b5 * r; r *= EM2;
    float b7 = b6 * r;
    u32x4 U;
    U[0] = __builtin_bit_cast(unsigned int, __builtin_amdgcn_cvt_pkrtz(b0, b1));
    U[1] = __builtin_bit_cast(unsigned int, __builtin_amdgcn_cvt_pkrtz(b2, b3));
    U[2] = __builtin_bit_cast(unsigned int, __builtin_amdgcn_cvt_pkrtz(b4, b5));
    U[3] = __builtin_bit_cast(unsigned int, __builtin_amdgcn_cvt_pkrtz(b6, b7));
    return __builtin_bit_cast(f16x8, U);
}

__device__ __forceinline__ float silu1(float xv) {
    float p = __builtin_amdgcn_exp2f(-xv * L2E);
    return xv * __builtin_amdgcn_rcpf(1.0f + p);
}

// 256 threads = 4 row-stacked waves; wave = 32 rows x 128 cols (m=1, nbb=4,
// d=1). Grid 512 -> 2 blocks/CU (64 KB LDS each) -> 8 waves/CU = 2/SIMD,
// 1 wave per block per SIMD; blocks time-staggered to anti-phase.
__global__ __launch_bounds__(256, 2) void kan_main(const float* __restrict__ x,
                                                   const _Float16* __restrict__ W3,
                                                   float* __restrict__ out) {
    __shared__ _Float16 smem[2][16384];   // 2 x 32 KB (8 k-step tiles each)

    const int tid   = threadIdx.x;
    const int lane  = tid & 63;
    const int w     = tid >> 6;
    const int l31   = lane & 31;
    const int sub   = lane >> 5;
    const int row0  = blockIdx.x * 128 + w * 32;
    const int start = blockIdx.x & 7;    // K-space rotation (L2 spread)

    // ---- time stagger: ~640 cyc per unit; differs across co-resident pair
    // whether pairing is {2i,2i+1} (bit0) or {i,i+256} (bit8) ----
    const int slp = (blockIdx.x & 1) + ((blockIdx.x >> 8) & 1);
    if (slp > 0) __builtin_amdgcn_s_sleep(10);
    if (slp > 1) __builtin_amdgcn_s_sleep(10);

    const float* xp = x + (size_t)(row0 + l31) * NIN;   // lane's x row

    f32x16 acc[4];
#pragma unroll
    for (int nbb = 0; nbb < 4; ++nbb)
#pragma unroll
        for (int r = 0; r < 16; ++r) acc[nbb][r] = 0.f;

    const char* wbase = (const char*)W3;
#define STAGE(buf, grp)                                                         \
    do {                                                                        \
        const char* _s = wbase + (size_t)(grp) * 32768 + (size_t)tid * 16;      \
        char*       _d = (char*)&smem[(buf)][0] + (size_t)tid * 16;             \
        _Pragma("unroll")                                                       \
        for (int _i = 0; _i < 8; ++_i) gll16(_s + _i * 4096, _d + _i * 4096);   \
    } while (0)

    STAGE(0, start);
    f32x4 xa = *(const f32x4*)(xp + start * 16 + sub * 8);
    f32x4 xb = *(const f32x4*)(xp + start * 16 + sub * 8 + 4);
    __syncthreads();

    // ---- 8 basis groups of 8 ksteps (K = 1024), rotated order ----
#pragma unroll
    for (int i = 0; i < 8; ++i) {
        const int cur  = i & 1;
        const int nxtg = (i < 7) ? ((start + i + 1) & 7) : 8;
        STAGE(cur ^ 1, nxtg);
        const int nxt = (i < 7) ? (((start + i + 1) & 7) * 16) : 0;
        f32x4 xa2 = *(const f32x4*)(xp + nxt + sub * 8);
        f32x4 xb2 = *(const f32x4*)(xp + nxt + sub * 8 + 4);

        const char* bpbase = (const char*)&smem[cur][0] + lane * 16;

        // software pipeline: a 2 ahead, b 1 ahead; VALU interleaves with MFMA
        f16x8 a[8];
        a[0] = basis8r(__builtin_fmaf(xa[0], 3.5f, 3.5f));
        a[1] = basis8r(__builtin_fmaf(xa[1], 3.5f, 3.5f));
        f16x8 b[4];
#pragma unroll
        for (int q = 0; q < 4; ++q) b[q] = *(const f16x8*)(bpbase + q * 1024);

#pragma unroll
        for (int t2 = 0; t2 < 8; ++t2) {
            f16x8 bn[4];
            if (t2 < 7) {
#pragma unroll
                for (int q = 0; q < 4; ++q)
                    bn[q] = *(const f16x8*)(bpbase + (t2 + 1) * 4096 + q * 1024);
            }
            if (t2 < 6) {
                float xs = (t2 + 2 < 4) ? xa[t2 + 2] : xb[(t2 + 2) & 3];
                a[t2 + 2] = basis8r(__builtin_fmaf(xs, 3.5f, 3.5f));
            }
#pragma unroll
            for (int q = 0; q < 4; ++q)
                acc[q] = __builtin_amdgcn_mfma_f32_32x32x16_f16(a[t2], b[q], acc[q], 0, 0, 0);
            if (t2 < 7) {
#pragma unroll
                for (int q = 0; q < 4; ++q) b[q] = bn[q];
            }
        }
        xa = xa2; xb = xb2;
        __syncthreads();
    }

    // ---- silu group: 8 ksteps (K = 128); buffer 0 holds tiles 64..71 ----
#pragma unroll
    for (int s = 0; s < 8; ++s) {
        f32x4 xa2, xb2;
        if (s < 7) {
            xa2 = *(const f32x4*)(xp + (s + 1) * 16 + sub * 8);
            xb2 = *(const f32x4*)(xp + (s + 1) * 16 + sub * 8 + 4);
        }
        u32x4 U;
        U[0] = __builtin_bit_cast(unsigned int,
               __builtin_amdgcn_cvt_pkrtz(silu1(xa[0]), silu1(xa[1])));
        U[1] = __builtin_bit_cast(unsigned int,
               __builtin_amdgcn_cvt_pkrtz(silu1(xa[2]), silu1(xa[3])));
        U[2] = __builtin_bit_cast(unsigned int,
               __builtin_amdgcn_cvt_pkrtz(silu1(xb[0]), silu1(xb[1])));
        U[3] = __builtin_bit_cast(unsigned int,
               __builtin_amdgcn_cvt_pkrtz(silu1(xb[2]), silu1(xb[3])));
        f16x8 a = __builtin_bit_cast(f16x8, U);
        const char* bp = (const char*)&smem[0][0] + s * 4096 + lane * 16;
#pragma unroll
        for (int q = 0; q < 4; ++q) {
            f16x8 bq = *(const f16x8*)(bp + q * 1024);
            acc[q] = __builtin_amdgcn_mfma_f32_32x32x16_f16(a, bq, acc[q], 0, 0, 0);
        }
        if (s < 7) { xa = xa2; xb = xb2; }
    }

    // ---- Epilogue: row = (r&3) + 8*(r>>2) + 4*sub, col = q*32 + l31 ----
#pragma unroll
    for (int q = 0; q < 4; ++q)
#pragma unroll
        for (int r = 0; r < 16; ++r) {
            int crow = (r & 3) + 8 * (r >> 2) + 4 * sub;
            out[(size_t)(row0 + crow) * NOUT + q * 32 + l31] = acc[q][r];
        }
}

extern "C" void kernel_launch(void* const* d_in, const int* in_sizes, int n_in,
                              void* d_out, int out_size, void* d_ws, size_t ws_size,
                              hipStream_t stream) {
    const float* x       = (const float*)d_in[0];
    const float* coeffs  = (const float*)d_in[1];
    const float* base_w  = (const float*)d_in[2];
    _Float16* W3 = (_Float16*)d_ws;   // 72 * 4096 = 294912 bytes

    kan_prep<<<dim3(72), dim3(256), 0, stream>>>(coeffs, base_w, W3);
    kan_main<<<dim3(BATCH / 128), dim3(256), 0, stream>>>(x, W3, (float*)d_out);
}

// Round 13
// 38.342 us; speedup vs baseline: 1.0397x; 1.0397x over previous
//
#include <hip/hip_runtime.h>

typedef __fp16       pk16x2 __attribute__((ext_vector_type(2)));
typedef _Float16     f16x8  __attribute__((ext_vector_type(8)));
typedef float        f32x4  __attribute__((ext_vector_type(4)));
typedef float        f32x16 __attribute__((ext_vector_type(16)));
typedef unsigned int u32x4  __attribute__((ext_vector_type(4)));

#define BATCH 65536
#define NIN   128
#define NOUT  128

#define L2E   1.4426950408889634f
#define SQL2E 1.2011224087864498f     /* sqrt(log2 e) */
#define EM2   0.1353352832366127f     /* e^-2 */

// ---------------------------------------------------------------------------
// MFMA 32x32x16 f16. A-frag: lane -> row = l&31, k = (l>>5)*8 + e.
// B-frag: lane -> col = l&31, k = (l>>5)*8 + e. C/D: col = l&31,
// row = (reg&3) + 8*(reg>>2) + 4*(l>>5).
//
// K-order (72 ksteps of 16): basis ks = g*8 + t2 (g=0..7):
//   k-slot sub*8+e -> j = g*16 + sub*8 + t2, grid = e
//   (lane consumes 8 CONSECUTIVE x floats per group). silu ks = 64+s:
//   j = s*16 + sub*8 + e.
//
// W3 (kan_prep): 72 tiles x 4 KB; tile ks, chunk c = nbb*64 + lane (16 B):
//   col = nbb*32 + (lane&31), sub = lane>>5:
//     ks < 64 : coeffs[col][(ks>>3)*16 + sub*8 + (ks&7)][e]
//     ks >= 64: base_w[col][(ks-64)*16 + sub*8 + e]
// Fragment ds_read: 64 lanes x 16 B consecutive -> conflict-free (verified).
//
// R13: SPLIT ACCUMULATORS — two acc banks alternating by kstep parity give
// 8 independent MFMA dependency chains per wave (4 was suspected to expose
// dependent-MFMA latency; R10's 2-chain config regressed, consistent).
// Banks summed in the epilogue; fp32 sum order change is within tolerance.
// ---------------------------------------------------------------------------

__global__ __launch_bounds__(256) void kan_prep(const float* __restrict__ coeffs,
                                                const float* __restrict__ base_w,
                                                _Float16* __restrict__ W3) {
    int t = blockIdx.x * 256 + threadIdx.x;   // chunk id, 0..18431
    int ks   = t >> 8;
    int c    = t & 255;
    int nbb  = c >> 6;
    int lane = c & 63;
    int sub  = lane >> 5;
    int col  = nbb * 32 + (lane & 31);
    f16x8 v;
    if (ks < 64) {
        int g = ks >> 3, t2 = ks & 7;
        const float* src = coeffs + ((size_t)col * 128 + g * 16 + sub * 8 + t2) * 8;
#pragma unroll
        for (int e = 0; e < 8; ++e) v[e] = (_Float16)src[e];
    } else {
        const float* src = base_w + (size_t)col * 128 + (ks - 64) * 16 + sub * 8;
#pragma unroll
        for (int e = 0; e < 8; ++e) v[e] = (_Float16)src[e];
    }
    *(f16x8*)((char*)W3 + (size_t)t * 16) = v;
}

__device__ __forceinline__ void gll16(const void* g, void* l) {
    __builtin_amdgcn_global_load_lds(
        (const __attribute__((address_space(1))) unsigned int*)g,
        (__attribute__((address_space(3))) unsigned int*)l, 16, 0, 0);
}

// b_g = exp(-(t-g)^2), t = 3.5*(x+1): 2 exp + mul chain; dword-packed result.
__device__ __forceinline__ f16x8 basis8r(float t) {
    float u  = t * SQL2E;
    float b0 = __builtin_amdgcn_exp2f(-(u * u));                              // e^{-t^2}
    float r  = __builtin_amdgcn_exp2f(__builtin_fmaf(t, 2.0f * L2E, -L2E));   // e^{2t-1}
    float b1 = b0 * r; r *= EM2;
    float b2 = b1 * r; r *= EM2;
    float b3 = b2 * r; r *= EM2;
    float b4 = b3 * r; r *= EM2;
    float b5 = b4 * r; r *= EM2;
    float b6 = b5 * r; r *= EM2;
    float b7 = b6 * r;
    u32x4 U;
    U[0] = __builtin_bit_cast(unsigned int, __builtin_amdgcn_cvt_pkrtz(b0, b1));
    U[1] = __builtin_bit_cast(unsigned int, __builtin_amdgcn_cvt_pkrtz(b2, b3));
    U[2] = __builtin_bit_cast(unsigned int, __builtin_amdgcn_cvt_pkrtz(b4, b5));
    U[3] = __builtin_bit_cast(unsigned int, __builtin_amdgcn_cvt_pkrtz(b6, b7));
    return __builtin_bit_cast(f16x8, U);
}

__device__ __forceinline__ float silu1(float xv) {
    float p = __builtin_amdgcn_exp2f(-xv * L2E);
    return xv * __builtin_amdgcn_rcpf(1.0f + p);
}

// 256 threads = 4 row-stacked waves. Wave owns 32 rows x 128 cols (m=1,
// nbb=4, d=1). Grid 512 -> 2 blocks/CU (64 KB LDS each) -> 8 waves/CU =
// 2/SIMD. 8 independent acc chains per wave (2 banks x 4 col-blocks).
__global__ __launch_bounds__(256, 2) void kan_main(const float* __restrict__ x,
                                                   const _Float16* __restrict__ W3,
                                                   float* __restrict__ out) {
    __shared__ _Float16 smem[2][16384];   // 2 x 32 KB (8 k-step tiles each)

    const int tid  = threadIdx.x;
    const int lane = tid & 63;
    const int w    = tid >> 6;
    const int l31  = lane & 31;
    const int sub  = lane >> 5;
    const int row0 = blockIdx.x * 128 + w * 32;

    const float* xp = x + (size_t)(row0 + l31) * NIN;   // lane's x row

    f32x16 accA[4], accB[4];
#pragma unroll
    for (int q = 0; q < 4; ++q)
#pragma unroll
        for (int r = 0; r < 16; ++r) { accA[q][r] = 0.f; accB[q][r] = 0.f; }

    const char* wbase = (const char*)W3;
#define STAGE(buf, grp)                                                         \
    do {                                                                        \
        const char* _s = wbase + (size_t)(grp) * 32768 + (size_t)tid * 16;      \
        char*       _d = (char*)&smem[(buf)][0] + (size_t)tid * 16;             \
        _Pragma("unroll")                                                       \
        for (int _i = 0; _i < 8; ++_i) gll16(_s + _i * 4096, _d + _i * 4096);   \
    } while (0)

    STAGE(0, 0);
    f32x4 xa = *(const f32x4*)(xp + sub * 8);
    f32x4 xb = *(const f32x4*)(xp + sub * 8 + 4);
    __syncthreads();

    // ---- 8 basis groups of 8 ksteps (K = 1024) ----
#pragma unroll
    for (int g = 0; g < 8; ++g) {
        const int cur = g & 1;
        STAGE(cur ^ 1, g + 1);            // g == 7 stages the silu group
        const int nxt = (g < 7) ? (g + 1) * 16 : 0;
        f32x4 xa2 = *(const f32x4*)(xp + nxt + sub * 8);
        f32x4 xb2 = *(const f32x4*)(xp + nxt + sub * 8 + 4);

        // pregenerate the group's 8 A-fragments (8 independent chains)
        f16x8 a[8];
#pragma unroll
        for (int t2 = 0; t2 < 4; ++t2) a[t2]     = basis8r(__builtin_fmaf(xa[t2], 3.5f, 3.5f));
#pragma unroll
        for (int t2 = 0; t2 < 4; ++t2) a[4 + t2] = basis8r(__builtin_fmaf(xb[t2], 3.5f, 3.5f));

        // MFMA cluster: kstep pairs; even kstep -> bank A, odd -> bank B.
        // All indices compile-time (full unroll) so accs stay in registers.
#pragma unroll
        for (int tp = 0; tp < 4; ++tp) {
            const char* bpa = (const char*)&smem[cur][0] + (tp * 2) * 4096 + lane * 16;
            const char* bpb = bpa + 4096;
#pragma unroll
            for (int q = 0; q < 4; ++q) {
                f16x8 b = *(const f16x8*)(bpa + q * 1024);
                accA[q] = __builtin_amdgcn_mfma_f32_32x32x16_f16(a[tp * 2], b, accA[q], 0, 0, 0);
            }
#pragma unroll
            for (int q = 0; q < 4; ++q) {
                f16x8 b = *(const f16x8*)(bpb + q * 1024);
                accB[q] = __builtin_amdgcn_mfma_f32_32x32x16_f16(a[tp * 2 + 1], b, accB[q], 0, 0, 0);
            }
        }
        xa = xa2; xb = xb2;
        __syncthreads();
    }

    // ---- silu group: 8 ksteps (K = 128); buffer 0 holds tiles 64..71 ----
#pragma unroll
    for (int sp = 0; sp < 4; ++sp) {
#pragma unroll
        for (int half = 0; half < 2; ++half) {
            const int s = sp * 2 + half;
            f32x4 xa2, xb2;
            if (s < 7) {
                xa2 = *(const f32x4*)(xp + (s + 1) * 16 + sub * 8);
                xb2 = *(const f32x4*)(xp + (s + 1) * 16 + sub * 8 + 4);
            }
            u32x4 U;
            U[0] = __builtin_bit_cast(unsigned int,
                   __builtin_amdgcn_cvt_pkrtz(silu1(xa[0]), silu1(xa[1])));
            U[1] = __builtin_bit_cast(unsigned int,
                   __builtin_amdgcn_cvt_pkrtz(silu1(xa[2]), silu1(xa[3])));
            U[2] = __builtin_bit_cast(unsigned int,
                   __builtin_amdgcn_cvt_pkrtz(silu1(xb[0]), silu1(xb[1])));
            U[3] = __builtin_bit_cast(unsigned int,
                   __builtin_amdgcn_cvt_pkrtz(silu1(xb[2]), silu1(xb[3])));
            f16x8 a = __builtin_bit_cast(f16x8, U);
            const char* bp = (const char*)&smem[0][0] + s * 4096 + lane * 16;
            if (half == 0) {
#pragma unroll
                for (int q = 0; q < 4; ++q) {
                    f16x8 bq = *(const f16x8*)(bp + q * 1024);
                    accA[q] = __builtin_amdgcn_mfma_f32_32x32x16_f16(a, bq, accA[q], 0, 0, 0);
                }
            } else {
#pragma unroll
                for (int q = 0; q < 4; ++q) {
                    f16x8 bq = *(const f16x8*)(bp + q * 1024);
                    accB[q] = __builtin_amdgcn_mfma_f32_32x32x16_f16(a, bq, accB[q], 0, 0, 0);
                }
            }
            if (s < 7) { xa = xa2; xb = xb2; }
        }
    }

    // ---- Epilogue: sum banks; row = (r&3) + 8*(r>>2) + 4*sub ----
#pragma unroll
    for (int q = 0; q < 4; ++q)
#pragma unroll
        for (int r = 0; r < 16; ++r) {
            int crow = (r & 3) + 8 * (r >> 2) + 4 * sub;
            out[(size_t)(row0 + crow) * NOUT + q * 32 + l31] = accA[q][r] + accB[q][r];
        }
}

extern "C" void kernel_launch(void* const* d_in, const int* in_sizes, int n_in,
                              void* d_out, int out_size, void* d_ws, size_t ws_size,
                              hipStream_t stream) {
    const float* x       = (const float*)d_in[0];
    const float* coeffs  = (const float*)d_in[1];
    const float* base_w  = (const float*)d_in[2];
    _Float16* W3 = (_Float16*)d_ws;   // 72 * 4096 = 294912 bytes

    kan_prep<<<dim3(72), dim3(256), 0, stream>>>(coeffs, base_w, W3);
    kan_main<<<dim3(BATCH / 128), dim3(256), 0, stream>>>(x, W3, (float*)d_out);
}